// Round 15
// baseline (16.544 us; speedup 1.0000x reference)
//
#include <hip/hip_runtime.h>
#include <hip/hip_bf16.h>

// Shapes: x,gn (8,128,64) f32; fb (1,128,32768) f32; resonance (64,128) f32.
// out (8,1,32768) f32.
// r[b,c,f] = sum_rr softmax(x+gn)[b,c,rr] * res[rr,f]
// out[b,s] = (1/128) * sum_c lerp(r[b,c,:], s) * fb[c,s]
//
// Fused v5 = R14 (16.2us, best) with the VGPR cap removed.
// R14 declared __launch_bounds__(512, 2) -> 128-VGPR cap, but p1 holds a
// 64-VGPR resonance cache (cr[4][4] float4) + 8 x/gn float4s + accs ->
// spills to scratch. Grid = 256 blocks = 1 block/CU, so the occupancy clamp
// bought nothing. v5: no min-waves arg (256-VGPR budget at 2 waves/SIMD),
// and p2 unroll widened 4 -> 8 for deeper load batching.
// Structure (proven in R14): 256 blocks (4 batch-pairs x 64 segs of 512
// samples) x 512 thr; p1 = coalesced quad-per-row redundant softmax (own 2
// batches only); p2 = 2 samples/thread, wave-uniform-broadcast b128 r-reads,
// float2 fb loads (sample on low lane bits); bp-major block order -> the 4
// blocks sharing a seg's fb slice land on one XCD (bi%8 == seg%8).

#define BATCH 8
#define BANDS 128
#define RES 64
#define NF 128
#define NS 32768
#define SEG 512
#define NSEG (NS / SEG)    // 64
#define NBP 4              // batch pairs
#define NTHR 512

__global__ __launch_bounds__(NTHR) void fused(const float* __restrict__ x,
                                              const float* __restrict__ gn,
                                              const float* __restrict__ fb,
                                              const float* __restrict__ res,
                                              float* __restrict__ out) {
    const int bi  = blockIdx.x;       // 0..255, bp-major
    const int bp  = bi >> 6;          // 0..3
    const int seg = bi & 63;          // 0..63
    const int tid = threadIdx.x;      // 0..511

    __shared__ float resc[4][RES];    // staged res columns [frame j][rr]
    __shared__ float r4[4][256];      // r per staged frame, row = bl*128+c

    const int fbase = 2 * seg - 1;    // lo in {2seg-1..2seg+1}; il=lo-fbase in 0..2

    if (tid < 4 * RES) {
        const int rr = tid >> 2, j = tid & 3;
        const int f = min(max(fbase + j, 0), NF - 1);
        resc[j][rr] = res[rr * NF + f];
    }
    __syncthreads();

    // ---- hoist this lane's resc slice (16 elems x 4 frames) to registers ----
    const int e0 = (tid & 3) * 16;    // elem-chunk start for this lane
    float4 cr[4][4];                  // [frame][j] over elems e0+4j..e0+4j+3
    #pragma unroll
    for (int f = 0; f < 4; ++f)
        #pragma unroll
        for (int j = 0; j < 4; ++j)
            cr[f][j] = *(const float4*)&resc[f][e0 + 4 * j];

    // ---- Phase 1: 256 rows (2 batches x 128 bands), 2 passes, 4 lanes/row ----
    const int q = tid >> 2;           // row-in-pass 0..127
    #pragma unroll
    for (int p = 0; p < 2; ++p) {
        const int row = p * 128 + q;  // 0..255
        const int bl  = row >> 7;
        const int c   = row & 127;
        const int bc  = (2 * bp + bl) * BANDS + c;

        const float4* __restrict__ xp = (const float4*)(x  + bc * RES + e0);
        const float4* __restrict__ gp = (const float4*)(gn + bc * RES + e0);

        float s = 0.f, d0 = 0.f, d1 = 0.f, d2 = 0.f, d3 = 0.f;
        #pragma unroll
        for (int j = 0; j < 4; ++j) {
            const float4 a = xp[j];
            const float4 b = gp[j];
            const float ex = __expf(a.x + b.x);
            const float ey = __expf(a.y + b.y);
            const float ez = __expf(a.z + b.z);
            const float ew = __expf(a.w + b.w);
            s += (ex + ey) + (ez + ew);
            d0 = fmaf(ex, cr[0][j].x, fmaf(ey, cr[0][j].y, fmaf(ez, cr[0][j].z, fmaf(ew, cr[0][j].w, d0))));
            d1 = fmaf(ex, cr[1][j].x, fmaf(ey, cr[1][j].y, fmaf(ez, cr[1][j].z, fmaf(ew, cr[1][j].w, d1))));
            d2 = fmaf(ex, cr[2][j].x, fmaf(ey, cr[2][j].y, fmaf(ez, cr[2][j].z, fmaf(ew, cr[2][j].w, d2))));
            d3 = fmaf(ex, cr[3][j].x, fmaf(ey, cr[3][j].y, fmaf(ez, cr[3][j].z, fmaf(ew, cr[3][j].w, d3))));
        }
        // reduce across the 4 lanes of the quad (lane bits 0-1)
        s  += __shfl_xor(s, 1);  s  += __shfl_xor(s, 2);
        d0 += __shfl_xor(d0, 1); d0 += __shfl_xor(d0, 2);
        d1 += __shfl_xor(d1, 1); d1 += __shfl_xor(d1, 2);
        d2 += __shfl_xor(d2, 1); d2 += __shfl_xor(d2, 2);
        d3 += __shfl_xor(d3, 1); d3 += __shfl_xor(d3, 2);

        if ((tid & 3) == 0) {
            const float inv = 1.0f / s;
            r4[0][row] = d0 * inv;
            r4[1][row] = d1 * inv;
            r4[2][row] = d2 * inv;
            r4[3][row] = d3 * inv;
        }
    }
    __syncthreads();

    // ---- Phase 2: thread = (bl = tid>>8, duo d = tid&255); samples s0,s0+1 ----
    const int bl = tid >> 8;
    const int d  = tid & 255;
    const int s0 = seg * SEG + 2 * d;

    float p0 = ((float)s0 + 0.5f) * (1.0f / 256.0f) - 0.5f;
    float p1 = ((float)s0 + 1.5f) * (1.0f / 256.0f) - 0.5f;
    p0 = fminf(fmaxf(p0, 0.0f), (float)(NF - 1));
    p1 = fminf(fmaxf(p1, 0.0f), (float)(NF - 1));
    const int lo = (int)floorf(p0);   // wave-uniform (128-sample wave spans
    const int il = lo - fbase;        //  never straddle s==127.5 mod 256)
    const float w0 = p0 - (float)lo;
    const float w1 = p1 - (float)lo;

    const float* __restrict__ rl = &r4[il][bl * BANDS];
    const float* __restrict__ rh = &r4[il + 1][bl * BANDS];

    float acc0 = 0.f, acc1 = 0.f;
    #pragma unroll 8
    for (int cc = 0; cc < BANDS / 4; ++cc) {
        const float4 rl4 = *(const float4*)&rl[4 * cc];   // broadcast b128
        const float4 rh4 = *(const float4*)&rh[4 * cc];   // broadcast b128
        const int band0 = 4 * cc;

        const float2 f0 = *(const float2*)&fb[(band0 + 0) * NS + s0];
        const float2 f1 = *(const float2*)&fb[(band0 + 1) * NS + s0];
        const float2 f2 = *(const float2*)&fb[(band0 + 2) * NS + s0];
        const float2 f3 = *(const float2*)&fb[(band0 + 3) * NS + s0];

        const float dx = rh4.x - rl4.x, dy = rh4.y - rl4.y;
        const float dz = rh4.z - rl4.z, dw = rh4.w - rl4.w;

        acc0 = fmaf(f0.x, fmaf(w0, dx, rl4.x), acc0);
        acc1 = fmaf(f0.y, fmaf(w1, dx, rl4.x), acc1);
        acc0 = fmaf(f1.x, fmaf(w0, dy, rl4.y), acc0);
        acc1 = fmaf(f1.y, fmaf(w1, dy, rl4.y), acc1);
        acc0 = fmaf(f2.x, fmaf(w0, dz, rl4.z), acc0);
        acc1 = fmaf(f2.y, fmaf(w1, dz, rl4.z), acc1);
        acc0 = fmaf(f3.x, fmaf(w0, dw, rl4.w), acc0);
        acc1 = fmaf(f3.y, fmaf(w1, dw, rl4.w), acc1);
    }

    float2 o;
    o.x = acc0 * (1.0f / (float)BANDS);
    o.y = acc1 * (1.0f / (float)BANDS);
    *(float2*)&out[(2 * bp + bl) * NS + s0] = o;
}

extern "C" void kernel_launch(void* const* d_in, const int* in_sizes, int n_in,
                              void* d_out, int out_size, void* d_ws, size_t ws_size,
                              hipStream_t stream) {
    const float* x   = (const float*)d_in[0];
    const float* gn  = (const float*)d_in[1];
    const float* fb  = (const float*)d_in[2];
    const float* res = (const float*)d_in[3];
    float* out = (float*)d_out;

    fused<<<NBP * NSEG, NTHR, 0, stream>>>(x, gn, fb, res, out);
}

// Round 16
// 13.585 us; speedup vs baseline: 1.2178x; 1.2178x over previous
//
#include <hip/hip_runtime.h>
#include <hip/hip_bf16.h>

// Shapes: x,gn (8,128,64) f32; fb (1,128,32768) f32; resonance (64,128) f32.
// out (8,1,32768) f32.
// r[b,c,f] = sum_rr softmax(x+gn)[b,c,rr] * res[rr,f]
// out[b,s] = (1/128) * sum_c lerp(r[b,c,:], s) * fb[c,s]
//
// Fused v6 = R14/R15 with p2's bl-duplication removed: one thread computes
// BOTH batches of its sample-duo (threads 0..255 active in p2; 256..511 only
// do p1). Halves p2's chip-wide VMEM (262K -> 131K wave-instrs) and DS b128
// streams; p2 math written as float2 ops to invite v_pk_fma_f32 packing.
// Everything else proven in R14 (16.2us best): 256 blocks (4 bp x 64 segs
// of 512) x 512 thr; p1 = coalesced quad-per-row redundant softmax over the
// block's 2 batches; bp-major order so same-seg blocks share an XCD.

#define BATCH 8
#define BANDS 128
#define RES 64
#define NF 128
#define NS 32768
#define SEG 512
#define NSEG (NS / SEG)    // 64
#define NBP 4              // batch pairs
#define NTHR 512

__device__ __forceinline__ float2 f2fma(float2 a, float2 b, float2 c) {
    float2 r;
    r.x = fmaf(a.x, b.x, c.x);
    r.y = fmaf(a.y, b.y, c.y);
    return r;
}

__global__ __launch_bounds__(NTHR) void fused(const float* __restrict__ x,
                                              const float* __restrict__ gn,
                                              const float* __restrict__ fb,
                                              const float* __restrict__ res,
                                              float* __restrict__ out) {
    const int bi  = blockIdx.x;       // 0..255, bp-major
    const int bp  = bi >> 6;          // 0..3
    const int seg = bi & 63;          // 0..63
    const int tid = threadIdx.x;      // 0..511

    __shared__ float resc[4][RES];    // staged res columns [frame j][rr]
    __shared__ float r4[4][256];      // r per staged frame, row = bl*128+c

    const int fbase = 2 * seg - 1;    // lo in {2seg-1..2seg+1}; il=lo-fbase in 0..2

    if (tid < 4 * RES) {
        const int rr = tid >> 2, j = tid & 3;
        const int f = min(max(fbase + j, 0), NF - 1);
        resc[j][rr] = res[rr * NF + f];
    }
    __syncthreads();

    // ---- hoist this lane's resc slice (16 elems x 4 frames) to registers ----
    const int e0 = (tid & 3) * 16;    // elem-chunk start for this lane
    float4 cr[4][4];                  // [frame][j] over elems e0+4j..e0+4j+3
    #pragma unroll
    for (int f = 0; f < 4; ++f)
        #pragma unroll
        for (int j = 0; j < 4; ++j)
            cr[f][j] = *(const float4*)&resc[f][e0 + 4 * j];

    // ---- Phase 1: 256 rows (2 batches x 128 bands), 2 passes, 4 lanes/row ----
    const int q = tid >> 2;           // row-in-pass 0..127
    #pragma unroll
    for (int p = 0; p < 2; ++p) {
        const int row = p * 128 + q;  // 0..255
        const int bl  = row >> 7;
        const int c   = row & 127;
        const int bc  = (2 * bp + bl) * BANDS + c;

        const float4* __restrict__ xp = (const float4*)(x  + bc * RES + e0);
        const float4* __restrict__ gp = (const float4*)(gn + bc * RES + e0);

        float s = 0.f, d0 = 0.f, d1 = 0.f, d2 = 0.f, d3 = 0.f;
        #pragma unroll
        for (int j = 0; j < 4; ++j) {
            const float4 a = xp[j];
            const float4 b = gp[j];
            const float ex = __expf(a.x + b.x);
            const float ey = __expf(a.y + b.y);
            const float ez = __expf(a.z + b.z);
            const float ew = __expf(a.w + b.w);
            s += (ex + ey) + (ez + ew);
            d0 = fmaf(ex, cr[0][j].x, fmaf(ey, cr[0][j].y, fmaf(ez, cr[0][j].z, fmaf(ew, cr[0][j].w, d0))));
            d1 = fmaf(ex, cr[1][j].x, fmaf(ey, cr[1][j].y, fmaf(ez, cr[1][j].z, fmaf(ew, cr[1][j].w, d1))));
            d2 = fmaf(ex, cr[2][j].x, fmaf(ey, cr[2][j].y, fmaf(ez, cr[2][j].z, fmaf(ew, cr[2][j].w, d2))));
            d3 = fmaf(ex, cr[3][j].x, fmaf(ey, cr[3][j].y, fmaf(ez, cr[3][j].z, fmaf(ew, cr[3][j].w, d3))));
        }
        s  += __shfl_xor(s, 1);  s  += __shfl_xor(s, 2);
        d0 += __shfl_xor(d0, 1); d0 += __shfl_xor(d0, 2);
        d1 += __shfl_xor(d1, 1); d1 += __shfl_xor(d1, 2);
        d2 += __shfl_xor(d2, 1); d2 += __shfl_xor(d2, 2);
        d3 += __shfl_xor(d3, 1); d3 += __shfl_xor(d3, 2);

        if ((tid & 3) == 0) {
            const float inv = 1.0f / s;
            r4[0][row] = d0 * inv;
            r4[1][row] = d1 * inv;
            r4[2][row] = d2 * inv;
            r4[3][row] = d3 * inv;
        }
    }
    __syncthreads();

    // ---- Phase 2: threads 0..255, thread = duo d; computes BOTH batches ----
    if (tid >= 256) return;

    const int d  = tid;               // 0..255
    const int s0 = seg * SEG + 2 * d;

    float p0 = ((float)s0 + 0.5f) * (1.0f / 256.0f) - 0.5f;
    float p1 = ((float)s0 + 1.5f) * (1.0f / 256.0f) - 0.5f;
    p0 = fminf(fmaxf(p0, 0.0f), (float)(NF - 1));
    p1 = fminf(fmaxf(p1, 0.0f), (float)(NF - 1));
    const int lo = (int)floorf(p0);   // wave-uniform (64 consecutive duos =
    const int il = lo - fbase;        //  a 128-aligned 128-sample run)
    float2 w01;
    w01.x = p0 - (float)lo;
    w01.y = p1 - (float)lo;

    const float* __restrict__ rl0 = &r4[il][0];        // batch 2bp
    const float* __restrict__ rh0 = &r4[il + 1][0];
    const float* __restrict__ rl1 = &r4[il][BANDS];    // batch 2bp+1
    const float* __restrict__ rh1 = &r4[il + 1][BANDS];

    float2 a0 = {0.f, 0.f}, a1 = {0.f, 0.f};
    #pragma unroll 4
    for (int cc = 0; cc < BANDS / 4; ++cc) {
        const float4 rl4_0 = *(const float4*)&rl0[4 * cc];   // broadcast b128
        const float4 rh4_0 = *(const float4*)&rh0[4 * cc];
        const float4 rl4_1 = *(const float4*)&rl1[4 * cc];
        const float4 rh4_1 = *(const float4*)&rh1[4 * cc];
        const int band0 = 4 * cc;

        const float2 f0 = *(const float2*)&fb[(band0 + 0) * NS + s0];
        const float2 f1 = *(const float2*)&fb[(band0 + 1) * NS + s0];
        const float2 f2 = *(const float2*)&fb[(band0 + 2) * NS + s0];
        const float2 f3 = *(const float2*)&fb[(band0 + 3) * NS + s0];

        // batch 0
        float2 t;
        t = f2fma(w01, make_float2(rh4_0.x - rl4_0.x, rh4_0.x - rl4_0.x),
                  make_float2(rl4_0.x, rl4_0.x));
        a0 = f2fma(f0, t, a0);
        t = f2fma(w01, make_float2(rh4_0.y - rl4_0.y, rh4_0.y - rl4_0.y),
                  make_float2(rl4_0.y, rl4_0.y));
        a0 = f2fma(f1, t, a0);
        t = f2fma(w01, make_float2(rh4_0.z - rl4_0.z, rh4_0.z - rl4_0.z),
                  make_float2(rl4_0.z, rl4_0.z));
        a0 = f2fma(f2, t, a0);
        t = f2fma(w01, make_float2(rh4_0.w - rl4_0.w, rh4_0.w - rl4_0.w),
                  make_float2(rl4_0.w, rl4_0.w));
        a0 = f2fma(f3, t, a0);

        // batch 1
        t = f2fma(w01, make_float2(rh4_1.x - rl4_1.x, rh4_1.x - rl4_1.x),
                  make_float2(rl4_1.x, rl4_1.x));
        a1 = f2fma(f0, t, a1);
        t = f2fma(w01, make_float2(rh4_1.y - rl4_1.y, rh4_1.y - rl4_1.y),
                  make_float2(rl4_1.y, rl4_1.y));
        a1 = f2fma(f1, t, a1);
        t = f2fma(w01, make_float2(rh4_1.z - rl4_1.z, rh4_1.z - rl4_1.z),
                  make_float2(rl4_1.z, rl4_1.z));
        a1 = f2fma(f2, t, a1);
        t = f2fma(w01, make_float2(rh4_1.w - rl4_1.w, rh4_1.w - rl4_1.w),
                  make_float2(rl4_1.w, rl4_1.w));
        a1 = f2fma(f3, t, a1);
    }

    const float sc = 1.0f / (float)BANDS;
    float2 o0, o1;
    o0.x = a0.x * sc; o0.y = a0.y * sc;
    o1.x = a1.x * sc; o1.y = a1.y * sc;
    *(float2*)&out[(2 * bp + 0) * NS + s0] = o0;
    *(float2*)&out[(2 * bp + 1) * NS + s0] = o1;
}

extern "C" void kernel_launch(void* const* d_in, const int* in_sizes, int n_in,
                              void* d_out, int out_size, void* d_ws, size_t ws_size,
                              hipStream_t stream) {
    const float* x   = (const float*)d_in[0];
    const float* gn  = (const float*)d_in[1];
    const float* fb  = (const float*)d_in[2];
    const float* res = (const float*)d_in[3];
    float* out = (float*)d_out;

    fused<<<NBP * NSEG, NTHR, 0, stream>>>(x, gn, fb, res, out);
}